// Round 6
// baseline (396.032 us; speedup 1.0000x reference)
//
#include <hip/hip_runtime.h>

#define PATCH_N 64
#define CH      4
#define PADDED  192
#define BATCH   512
#define ROWS_PB 48                        // canvas rows per block (quarter canvas)
#define THREADS 512                       // 8 waves
#define CFLOATS (ROWS_PB * PADDED)        // 9216 floats = 36,864 B LDS

__device__ __forceinline__ int   rfl_i(int x)   { return __builtin_amdgcn_readfirstlane(x); }
__device__ __forceinline__ float rfl_f(float x) { return __int_as_float(__builtin_amdgcn_readfirstlane(__float_as_int(x))); }

// Scatter formulation. Patch pixel (r, p, c) contributes to exactly 4 output
// pixels with per-channel-constant weight products:
//   out(r+sy,   p+sx  ) += wy0*wx0*v    out(r+sy,   p+sx-1) += wy0*wx1*v
//   out(r-1+sy, p+sx  ) += wy1*wx0*v    out(r-1+sy, p+sx-1) += wy1*wx1*v
// (sx,sy in [2,127] so all targets lie in [1,190] -- no clipping needed, and
// zero-fill outside the patch is automatic: we only scatter existing pixels.)
// One block accumulates one 48-row output slab in an LDS canvas via
// ds_add_f32 (lane -> consecutive cols; races across waves/channels are
// resolved by the HW atomic), then flushes with coalesced float4 stores.
// Patches are read as float4 (all 4 channels per load, 100% line use).
// 36.9 KB LDS + 512 thr + low VGPR -> 4 blocks/CU = 32 waves/CU, entire
// 2048-block grid resident.
__global__ __launch_bounds__(THREADS, 8)
void reassemble_scatter(const float* __restrict__ patches,
                        const float* __restrict__ positions,
                        float* __restrict__ out)
{
    __shared__ float canvas[CFLOATS];

    const int blk  = blockIdx.x;
    const int b    = blk >> 2;
    const int Y0   = (blk & 3) * ROWS_PB;
    const int tid  = threadIdx.x;
    const int lane = tid & 63;
    const int wid  = rfl_i(tid >> 6);     // 0..7

    // ---- zero canvas (2304 float4s / 512 threads = 4.5 -> guarded 5 iters)
    float4* cz = reinterpret_cast<float4*>(canvas);
#pragma unroll
    for (int j = 0; j < CFLOATS / 4 / THREADS + 1; ++j) {
        const int idx = j * THREADS + tid;
        if (idx < CFLOATS / 4) cz[idx] = make_float4(0.f, 0.f, 0.f, 0.f);
    }

    // ---- per-channel uniform constants (SGPR via readfirstlane)
    const float* pos = positions + (size_t)b * 8;   // (1,2,C): dx[c], then dy[c]
    int   syc[CH];
    float w00[CH], w01[CH], w10[CH], w11[CH];       // wyS * wxT products
    int   colb[CH];                                 // per-lane canvas col byte base (x = sx-1+lane)
#pragma unroll
    for (int c = 0; c < CH; ++c) {
        const float tx  = 64.f + rfl_f(pos[c]);
        const float sxf = ceilf(tx);
        const int   sx  = rfl_i((int)sxf);
        const float wx1 = rfl_f(sxf - tx);
        const float wx0 = 1.f - wx1;

        const float ty  = 64.f + rfl_f(pos[CH + c]);
        const float syf = ceilf(ty);
        syc[c] = rfl_i((int)syf);
        const float wy1 = rfl_f(syf - ty);
        const float wy0 = 1.f - wy1;

        w00[c] = wy0 * wx0;  w01[c] = wy0 * wx1;
        w10[c] = wy1 * wx0;  w11[c] = wy1 * wx1;
        colb[c] = (sx - 1 + lane) * 4;
    }

    __syncthreads();

    // patch row r, col lane, all 4 channels in one float4
    const float4* prow = reinterpret_cast<const float4*>(patches)
                       + (size_t)b * PATCH_N * PATCH_N + lane;

#pragma unroll
    for (int i = 0; i < PATCH_N / 8; ++i) {
        const int r = i * 8 + wid;                  // wave-uniform patch row
        const float4 f4 = prow[(size_t)r * PATCH_N];
#pragma unroll
        for (int c = 0; c < CH; ++c) {
            const float v = (c == 0) ? f4.x : (c == 1) ? f4.y : (c == 2) ? f4.z : f4.w;

            // side 0: this row is the TOP tap (iy0 = r) of output row r+sy
            {
                const int yl = r + syc[c] - Y0;     // SALU + s_cbranch (uniform)
                if ((unsigned)yl < (unsigned)ROWS_PB) {
                    float* base = (float*)((char*)canvas + yl * (PADDED * 4) + colb[c]);
                    atomicAdd(base,     w01[c] * v);   // col sx-1+lane: weight wx1
                    atomicAdd(base + 1, w00[c] * v);   // col sx  +lane: weight wx0
                }
            }
            // side 1: this row is the BOTTOM tap (iy0+1 = r) of output row r-1+sy
            {
                const int yl = r - 1 + syc[c] - Y0;
                if ((unsigned)yl < (unsigned)ROWS_PB) {
                    float* base = (float*)((char*)canvas + yl * (PADDED * 4) + colb[c]);
                    atomicAdd(base,     w11[c] * v);
                    atomicAdd(base + 1, w10[c] * v);
                }
            }
        }
    }

    __syncthreads();

    // ---- flush slab: coalesced float4 stores (1 KB per wave-instruction)
    const float4* cs = reinterpret_cast<const float4*>(canvas);
    float4* dst = reinterpret_cast<float4*>(out) + (size_t)blk * (CFLOATS / 4);
#pragma unroll
    for (int j = 0; j < CFLOATS / 4 / THREADS + 1; ++j) {
        const int idx = j * THREADS + tid;
        if (idx < CFLOATS / 4) dst[idx] = cs[idx];
    }
}

extern "C" void kernel_launch(void* const* d_in, const int* in_sizes, int n_in,
                              void* d_out, int out_size, void* d_ws, size_t ws_size,
                              hipStream_t stream) {
    const float* patches   = (const float*)d_in[0];
    const float* positions = (const float*)d_in[1];
    float* out = (float*)d_out;

    reassemble_scatter<<<dim3(BATCH * 4), THREADS, 0, stream>>>(patches, positions, out);
}

// Round 7
// 102.534 us; speedup vs baseline: 3.8624x; 3.8624x over previous
//
#include <hip/hip_runtime.h>

#define PATCH_N 64
#define CH      4
#define PADDED  192
#define BATCH   512
#define THREADS 1024
#define RSTRIDE 76                       // padded row stride (floats), mult of 4
#define PLANE_F (PATCH_N * RSTRIDE)      // 4864 floats per channel plane
#define LDS_F   (CH * PLANE_F)           // 19456 floats = 77,824 B

__device__ __forceinline__ int   rfl_i(int x)   { return __builtin_amdgcn_readfirstlane(x); }
__device__ __forceinline__ float rfl_f(float x) { return __int_as_float(__builtin_amdgcn_readfirstlane(__float_as_int(x))); }

// Gather with alignment-shifted LDS planes. Channel c's 64x64 plane is stored
// at column offset (sx[c]&3)+4 within 76-float rows, so the 5-tap window for
// any 16B-aligned output group starts 16B-aligned -> ds_read_b128 + ds_read_b32
// per row (4 LDS instrs per channel-visit, covering 4 outputs). Pad columns are
// zeroed: every OOB tap reads 0 with an exact-0 weight (NaN-safe). Each thread
// produces one float4 of the canvas -> waves store 1 KB contiguous dwordx4.
// 77.8 KB LDS x 2 blocks fits 160 KB -> 2 blocks/CU, 32 waves/CU.
__global__ __launch_bounds__(THREADS, 8)
void reassemble_v7(const float* __restrict__ patches,
                   const float* __restrict__ positions,
                   float* __restrict__ out)
{
    __shared__ float4 lds4[LDS_F / 4];
    float* __restrict__ lds = reinterpret_cast<float*>(lds4);

    const int b   = blockIdx.x;
    const int tid = threadIdx.x;

    // ---- per-channel scalar constants ----
    const float* pos = positions + (size_t)b * 8;     // (1,2,C): dx[c] then dy[c]
    int   syc[CH], sxc[CH], pc[CH], Qc[CH];
    float wx0c[CH], wx1c[CH], wy0c[CH], wy1c[CH];
#pragma unroll
    for (int c = 0; c < CH; ++c) {
        const float tx  = 64.f + rfl_f(pos[c]);
        const float sxf = ceilf(tx);
        sxc[c]  = rfl_i((int)sxf);
        wx1c[c] = rfl_f(sxf - tx);
        wx0c[c] = 1.f - wx1c[c];
        const float ty  = 64.f + rfl_f(pos[CH + c]);
        const float syf = ceilf(ty);
        syc[c]  = rfl_i((int)syf);
        wy1c[c] = rfl_f(syf - ty);
        wy0c[c] = 1.f - wy1c[c];
        pc[c] = sxc[c] & 3;
        Qc[c] = 4 - (sxc[c] & ~3);       // window start: q = x0 + Qc (mult of 4)
    }

    // ---- zero pad columns: [0..p+3] and [p+68..75] of every row/plane ----
    {
        const int row = tid / 12;        // threads 0..767 active (64 rows x 12 cols)
        const int m   = tid - row * 12;
#pragma unroll
        for (int c = 0; c < CH; ++c) {
            if (tid < 768) {
                const int col = (m <= pc[c] + 3) ? m : (m + 64);
                lds[c * PLANE_F + row * RSTRIDE + col] = 0.f;
            }
        }
    }
    __syncthreads();

    // ---- stage: pixel float4 -> 4 shifted planes (conflict-free ds_write) ----
    const float4* __restrict__ p4 =
        reinterpret_cast<const float4*>(patches) + (size_t)b * (PATCH_N * PATCH_N);
#pragma unroll
    for (int i = 0; i < (PATCH_N * PATCH_N) / THREADS; ++i) {   // 4 iters
        const int pix = i * THREADS + tid;
        const int r   = pix >> 6;
        const int xcl = pix & 63;
        const float4 v = p4[pix];
        lds[0 * PLANE_F + r * RSTRIDE + xcl + pc[0] + 4] = v.x;
        lds[1 * PLANE_F + r * RSTRIDE + xcl + pc[1] + 4] = v.y;
        lds[2 * PLANE_F + r * RSTRIDE + xcl + pc[2] + 4] = v.z;
        lds[3 * PLANE_F + r * RSTRIDE + xcl + pc[3] + 4] = v.w;
    }
    __syncthreads();

    float4* __restrict__ o4 =
        reinterpret_cast<float4*>(out) + (size_t)b * (PADDED * PADDED / 4);

#pragma unroll
    for (int it = 0; it < (PADDED * PADDED / 4) / THREADS; ++it) {  // 9 iters
        const int idx = it * THREADS + tid;       // float4 index in canvas
        const int y   = idx / 48;                 // row (varies per lane)
        const int x0  = (idx - y * 48) << 2;      // first output col of this group
        float a0 = 0.f, a1 = 0.f, a2 = 0.f, a3 = 0.f;

#pragma unroll
        for (int c = 0; c < CH; ++c) {
            const int r0 = y - syc[c];            // top tap row
            const int j0 = x0 - sxc[c];           // left tap col
            const bool act = ((unsigned)(r0 + 1) <= 64u) && ((unsigned)(j0 + 4) <= 67u);
            if (__ballot(act) == 0ull) continue;  // wave-level skip

            const int q   = min(max(x0 + Qc[c], 0), 68);   // aligned window start
            const int r0c = min(max(r0, 0), 63);
            const int r1c = min(max(r0 + 1, 0), 63);
            const int A0  = c * PLANE_F + r0c * RSTRIDE + q;
            const int A1  = c * PLANE_F + r1c * RSTRIDE + q;
            const float4 W0  = lds4[A0 >> 2];     // ds_read_b128 (cols q..q+3)
            const float  W04 = lds[A0 + 4];       // ds_read_b32  (col q+4)
            const float4 W1  = lds4[A1 >> 2];
            const float  W14 = lds[A1 + 4];

            const float wy0m = ((unsigned)r0       < 64u) ? wy0c[c] : 0.f;
            const float wy1m = ((unsigned)(r0 + 1) < 64u) ? wy1c[c] : 0.f;

            const bool v0 = (unsigned)(j0    ) < 64u;
            const bool v1 = (unsigned)(j0 + 1) < 64u;
            const bool v2 = (unsigned)(j0 + 2) < 64u;
            const bool v3 = (unsigned)(j0 + 3) < 64u;
            const bool v4 = (unsigned)(j0 + 4) < 64u;
            const float wx0 = wx0c[c], wx1 = wx1c[c];
            const float l0 = v0 ? wx0 : 0.f, rw0 = v1 ? wx1 : 0.f;
            const float l1 = v1 ? wx0 : 0.f, rw1 = v2 ? wx1 : 0.f;
            const float l2 = v2 ? wx0 : 0.f, rw2 = v3 ? wx1 : 0.f;
            const float l3 = v3 ? wx0 : 0.f, rw3 = v4 ? wx1 : 0.f;

            float t0, t1;
            t0 = fmaf(rw0, W0.y, l0 * W0.x);  t1 = fmaf(rw0, W1.y, l0 * W1.x);
            a0 = fmaf(wy0m, t0, fmaf(wy1m, t1, a0));
            t0 = fmaf(rw1, W0.z, l1 * W0.y);  t1 = fmaf(rw1, W1.z, l1 * W1.y);
            a1 = fmaf(wy0m, t0, fmaf(wy1m, t1, a1));
            t0 = fmaf(rw2, W0.w, l2 * W0.z);  t1 = fmaf(rw2, W1.w, l2 * W1.z);
            a2 = fmaf(wy0m, t0, fmaf(wy1m, t1, a2));
            t0 = fmaf(rw3, W04,  l3 * W0.w);  t1 = fmaf(rw3, W14,  l3 * W1.w);
            a3 = fmaf(wy0m, t0, fmaf(wy1m, t1, a3));
        }

        o4[idx] = make_float4(a0, a1, a2, a3);    // 1 KB contiguous per wave
    }
}

extern "C" void kernel_launch(void* const* d_in, const int* in_sizes, int n_in,
                              void* d_out, int out_size, void* d_ws, size_t ws_size,
                              hipStream_t stream) {
    const float* patches   = (const float*)d_in[0];
    const float* positions = (const float*)d_in[1];
    float* out = (float*)d_out;

    reassemble_v7<<<dim3(BATCH), THREADS, 0, stream>>>(patches, positions, out);
}

// Round 8
// 98.250 us; speedup vs baseline: 4.0309x; 1.0436x over previous
//
#include <hip/hip_runtime.h>

#define PATCH_N 64
#define CH      4
#define PADDED  192
#define BATCH   512
#define THREADS 1024
#define PROWS   66                        // guard row 0, data rows 1..64, guard 65
#define PCOLS   76                        // guard cols + shifted 65-col data window
#define PLANE_F (PROWS * PCOLS)           // 5016 floats per channel plane
#define LDS_F   (CH * PLANE_F)            // 20064 floats = 80,256 B

__device__ __forceinline__ int   rfl_i(int x)   { return __builtin_amdgcn_readfirstlane(x); }
__device__ __forceinline__ float rfl_f(float x) { return __int_as_float(__builtin_amdgcn_readfirstlane(__float_as_int(x))); }

// H-plane gather. During staging, each patch row is horizontally pre-blended:
//   H_c(r, j) = wx0*P(r,j) + wx1*P(r,j+1),  j in [-1, 63]
// (one shfl_down + fma per channel per pixel) and stored alignment-shifted so
// that output group x0 (mult of 4) reads its 4 taps as ONE aligned
// ds_read_b128 at plane col 4*(xg - a_c + 1). Guard rows (patch rows -1, 64)
// and guard cols are zeroed, so out-of-footprint taps contribute exact 0 with
// NO masks: inner body per channel = 2 clamps + 2 ds_read_b128 + 8 fma.
//   out(y,x) = sum_c wy0_c*H_c(y-sy_c, x) + wy1_c*H_c(y-sy_c+1, x)
// y-window skip is scalar (readfirstlane bound vs sy). 80,256 B LDS x 2
// blocks fits 160 KiB -> 2 blocks/CU, 32 waves/CU.
__global__ __launch_bounds__(THREADS, 8)
void reassemble_h(const float* __restrict__ patches,
                  const float* __restrict__ positions,
                  float* __restrict__ out)
{
    __shared__ float4 lds4[LDS_F / 4];
    float* __restrict__ lds = reinterpret_cast<float*>(lds4);

    const int b    = blockIdx.x;
    const int tid  = threadIdx.x;
    const int lane = tid & 63;
    const int wid  = rfl_i(tid >> 6);     // 0..15

    // ---- per-channel uniform constants (SGPR) ----
    const float* pos = positions + (size_t)b * 8;   // (1,2,C): dx[c] then dy[c]
    int   syc[CH], ac[CH], padc[CH];
    float wx0c[CH], wx1c[CH], wy0c[CH], wy1c[CH];
#pragma unroll
    for (int c = 0; c < CH; ++c) {
        const float tx  = 64.f + rfl_f(pos[c]);
        const float sxf = ceilf(tx);
        const int   sx  = rfl_i((int)sxf);            // in [2,127]
        wx1c[c] = rfl_f(sxf - tx);
        wx0c[c] = 1.f - wx1c[c];
        const float ty  = 64.f + rfl_f(pos[CH + c]);
        const float syf = ceilf(ty);
        syc[c]  = rfl_i((int)syf);
        wy1c[c] = rfl_f(syf - ty);
        wy0c[c] = 1.f - wy1c[c];
        ac[c]   = (sx - 1) >> 2;          // alignment block of left data col
        padc[c] = (sx - 1) & 3;           // column shift within 16B
    }

    // ---- zero all planes (guards stay zero; data overwritten below) ----
#pragma unroll
    for (int j = 0; j < (LDS_F / 4 + THREADS - 1) / THREADS; ++j) {   // 5 iters
        const int idx = j * THREADS + tid;
        if (idx < LDS_F / 4) lds4[idx] = make_float4(0.f, 0.f, 0.f, 0.f);
    }
    __syncthreads();

    // ---- stage + horizontal pre-blend: patch row r, lane = col ----
    const float4* __restrict__ p4 =
        reinterpret_cast<const float4*>(patches) + (size_t)b * (PATCH_N * PATCH_N);
    const bool last = (lane == 63);
#pragma unroll
    for (int pass = 0; pass < 4; ++pass) {
        const int r = pass * 16 + wid;                // wave-uniform row
        const float4 v = p4[r * PATCH_N + lane];      // coalesced 1 KB/wave
#pragma unroll
        for (int c = 0; c < CH; ++c) {
            const float val = (c == 0) ? v.x : (c == 1) ? v.y : (c == 2) ? v.z : v.w;
            float vr = __shfl_down(val, 1);           // P(r, lane+1)
            vr = last ? 0.f : vr;                     // P(r,64) = 0
            const float h = fmaf(wx1c[c], vr, wx0c[c] * val);   // H(r, lane)
            float* pl = lds + c * PLANE_F + (r + 1) * PCOLS;
            pl[lane + padc[c] + 5] = h;               // data col for j=lane
            if (lane == 0) pl[padc[c] + 4] = wx1c[c] * val;     // H(r,-1)
        }
    }
    __syncthreads();

    // ---- compute: each thread one output float4 per iter ----
    float4* __restrict__ o4 =
        reinterpret_cast<float4*>(out) + (size_t)b * (PADDED * PADDED / 4);

#pragma unroll
    for (int it = 0; it < (PADDED * PADDED / 4) / THREADS; ++it) {   // 9 iters
        const int idx = it * THREADS + tid;
        const int y   = idx / 48;                     // row (monotone in lane)
        const int xg  = idx - y * 48;                 // float4 group in row
        const int y0  = rfl_i(y);                     // wave min-y (lane0)
        const int yp1 = y + 1;
        float a0 = 0.f, a1 = 0.f, a2 = 0.f, a3 = 0.f;

#pragma unroll
        for (int c = 0; c < CH; ++c) {
            // wave y-range [y0, y0+2] vs channel window [sy-1, sy+63]: scalar skip
            if (y0 + 2 < syc[c] - 1 || y0 > syc[c] + 63) continue;

            const int t    = yp1 - syc[c];            // plane row of top tap
            const int row0 = min(max(t, 0), 65);      // clamp -> guard rows
            const int row1 = min(max(t, -1), 64) + 1; // independent clamp
            const int q4   = min(max(xg - ac[c] + 1, 0), 18);  // aligned col grp
            const int base = c * (PLANE_F / 4) + q4;  // float4 index
            const float4 W0 = lds4[base + row0 * (PCOLS / 4)]; // ds_read_b128
            const float4 W1 = lds4[base + row1 * (PCOLS / 4)];

            const float wy0 = wy0c[c], wy1 = wy1c[c];
            a0 = fmaf(wy0, W0.x, a0); a0 = fmaf(wy1, W1.x, a0);
            a1 = fmaf(wy0, W0.y, a1); a1 = fmaf(wy1, W1.y, a1);
            a2 = fmaf(wy0, W0.z, a2); a2 = fmaf(wy1, W1.z, a2);
            a3 = fmaf(wy0, W0.w, a3); a3 = fmaf(wy1, W1.w, a3);
        }

        o4[idx] = make_float4(a0, a1, a2, a3);        // 1 KB contiguous per wave
    }
}

extern "C" void kernel_launch(void* const* d_in, const int* in_sizes, int n_in,
                              void* d_out, int out_size, void* d_ws, size_t ws_size,
                              hipStream_t stream) {
    const float* patches   = (const float*)d_in[0];
    const float* positions = (const float*)d_in[1];
    float* out = (float*)d_out;

    reassemble_h<<<dim3(BATCH), THREADS, 0, stream>>>(patches, positions, out);
}